// Round 2
// baseline (1761.486 us; speedup 1.0000x reference)
//
#include <hip/hip_runtime.h>
#include <math.h>

// ---------- types / helpers ----------
typedef float  floatx4 __attribute__((ext_vector_type(4)));
typedef short  shortx8 __attribute__((ext_vector_type(8)));
typedef __bf16 bf16x8  __attribute__((ext_vector_type(8)));

static __device__ __forceinline__ floatx4 mfma16(shortx8 a, shortx8 b, floatx4 c) {
  return __builtin_amdgcn_mfma_f32_16x16x32_bf16(
      __builtin_bit_cast(bf16x8, a), __builtin_bit_cast(bf16x8, b), c, 0, 0, 0);
}
static __device__ __forceinline__ unsigned short f2bf(float f) {
  unsigned int u = __builtin_bit_cast(unsigned int, f);
  u += 0x7fffu + ((u >> 16) & 1u);           // RNE to bf16
  return (unsigned short)(u >> 16);
}
static __device__ __forceinline__ float bf2f(unsigned short h) {
  unsigned int u = ((unsigned int)h) << 16;
  return __builtin_bit_cast(float, u);
}
static __device__ __forceinline__ unsigned int packbf2(float lo, float hi) {
  return (unsigned int)f2bf(lo) | ((unsigned int)f2bf(hi) << 16);
}

// ---------- GEMM: C[M,Nn] = A[M,K(lda)] * B[K,Nn] ; bf16 MFMA, fp32 acc ----------
// 128x128 tile, BK=32, 256 threads (4 waves, 2x2), LDS stride 40 shorts (80B) vs bank conflicts.
template<int A_BF16, int C_BF16>
__global__ __launch_bounds__(256) void gemm_kernel(const void* __restrict__ Ap,
                                                   const float* __restrict__ Bp,
                                                   void* __restrict__ Cp,
                                                   int M, int Nn, int K, int lda) {
  __shared__ alignas(16) short As[128 * 40];
  __shared__ alignas(16) short Bs[128 * 40];
  const int tid = threadIdx.x;
  const int lane = tid & 63, w = tid >> 6;
  const int l15 = lane & 15, lg = lane >> 4;
  const int wr = w >> 1, wc = w & 1;
  const long m0 = (long)blockIdx.x * 128;
  const long n0 = (long)blockIdx.y * 128;

  floatx4 acc[4][4];
#pragma unroll
  for (int m = 0; m < 4; ++m)
#pragma unroll
    for (int n = 0; n < 4; ++n) acc[m][n] = (floatx4)0.0f;

  for (int k0 = 0; k0 < K; k0 += 32) {
    // ---- stage A tile [128 rows][32 k] as bf16, LDS layout As[row][k], stride 40
    if constexpr (A_BF16) {
      const unsigned short* A = (const unsigned short*)Ap;
#pragma unroll
      for (int i = 0; i < 2; ++i) {
        int qi = tid + 256 * i;            // 512 chunks of 8 elems
        int row = qi >> 2, ch = qi & 3;
        uint4 v = *(const uint4*)(A + (m0 + row) * (long)lda + k0 + ch * 8);
        *(uint4*)((char*)As + row * 80 + ch * 16) = v;
      }
    } else {
      const float* A = (const float*)Ap;
#pragma unroll
      for (int i = 0; i < 4; ++i) {
        int qi = tid + 256 * i;            // 1024 float4 quads
        int row = qi >> 3, q = qi & 7;
        float4 v = *(const float4*)(A + (m0 + row) * (long)lda + k0 + q * 4);
        uint2 st;
        st.x = packbf2(v.x, v.y);
        st.y = packbf2(v.z, v.w);
        *(uint2*)((char*)As + row * 80 + q * 8) = st;
      }
    }
    // ---- stage B tile [32 k][128 col] transposed into Bs[col][k] (k-pairs packed as b32)
#pragma unroll
    for (int i = 0; i < 2; ++i) {
      int qi = tid + 256 * i;              // 512 tasks: 16 k-pairs x 32 col-quads
      int kp = qi >> 5, q = qi & 31;
      const float* B0 = Bp + (long)(k0 + 2 * kp) * Nn + n0 + q * 4;
      float4 a = *(const float4*)B0;
      float4 b = *(const float4*)(B0 + Nn);
      const float* af_ = (const float*)&a;
      const float* bf_ = (const float*)&b;
#pragma unroll
      for (int j = 0; j < 4; ++j) {
        int col = q * 4 + j;
        *(unsigned int*)((char*)Bs + col * 80 + kp * 4) = packbf2(af_[j], bf_[j]);
      }
    }
    __syncthreads();

    shortx8 afr[4], bfr[4];
#pragma unroll
    for (int m = 0; m < 4; ++m) {
      int row = wr * 64 + m * 16 + l15;
      afr[m] = *(const shortx8*)((char*)As + row * 80 + lg * 16);
    }
#pragma unroll
    for (int n = 0; n < 4; ++n) {
      int col = wc * 64 + n * 16 + l15;
      bfr[n] = *(const shortx8*)((char*)Bs + col * 80 + lg * 16);
    }
#pragma unroll
    for (int m = 0; m < 4; ++m)
#pragma unroll
      for (int n = 0; n < 4; ++n)
        acc[m][n] = mfma16(afr[m], bfr[n], acc[m][n]);
    __syncthreads();
  }

  // ---- epilogue: C/D layout col=lane&15, row=(lane>>4)*4+r
#pragma unroll
  for (int m = 0; m < 4; ++m)
#pragma unroll
    for (int n = 0; n < 4; ++n)
#pragma unroll
      for (int r = 0; r < 4; ++r) {
        long row = m0 + wr * 64 + m * 16 + lg * 4 + r;
        long col = n0 + wc * 64 + n * 16 + l15;
        float val = acc[m][n][r];
        if constexpr (C_BF16) ((unsigned short*)Cp)[row * Nn + col] = f2bf(val);
        else                  ((float*)Cp)[row * Nn + col] = val;
      }
}

// ---------- RoPE (llama3 scaling), in-place on q (cols 0..4095) and k (4096..5119) ----------
__global__ __launch_bounds__(256) void rope_kernel(unsigned short* __restrict__ qkv,
                                                   const int* __restrict__ pos) {
  const int token = blockIdx.x;            // 0..4095 = b*2048+n
  const int tid = threadIdx.x;
  __shared__ float cs[64], sn[64];
  if (tid < 64) {
    float d = (float)tid;
    float inv = powf(500000.0f, -d * (1.0f / 64.0f));
    float wl = 6.283185307179586f / inv;
    float scaled;
    if (wl > 8192.0f) scaled = inv * 0.125f;
    else if (wl < 2048.0f) scaled = inv;
    else {
      float smooth = (8192.0f / wl - 1.0f) * (1.0f / 3.0f);
      scaled = (1.0f - smooth) * inv * 0.125f + smooth * inv;
    }
    float ang = (float)pos[token] * scaled;
    cs[tid] = cosf(ang);
    sn[tid] = sinf(ang);
  }
  __syncthreads();
  const long base = (long)token * 6144;
#pragma unroll
  for (int it = 0; it < 10; ++it) {        // 40 heads * 64 pairs = 2560 / 256
    int p = tid + 256 * it;
    int h = p >> 6, d = p & 63;
    long i0 = base + h * 128 + d;
    float a = bf2f(qkv[i0]);
    float b = bf2f(qkv[i0 + 64]);
    float c = cs[d], s = sn[d];
    qkv[i0]      = f2bf(a * c - b * s);
    qkv[i0 + 64] = f2bf(b * c + a * s);
  }
}

// ---------- causal GQA flash attention ----------
// block = (qblk, qhead, batch); 4 waves x 16 q-rows; KV tile = 64 tokens.
// O is written IN PLACE into the q-region of qkv (sole reader = this block, read at start).
#define SCALE_QK 0.08838834764831845f
__global__ __launch_bounds__(256) void attn_kernel(unsigned short* __restrict__ qkv) {
  const int tid = threadIdx.x;
  const int w = tid >> 6, lane = tid & 63;
  const int l15 = lane & 15, lg = lane >> 4;
  const int qblk = blockIdx.x, qh = blockIdx.y, b = blockIdx.z;
  const int kvh = qh >> 2;
  const int q0 = qblk * 64;
  const long rowbase = (long)b * 2048;

  __shared__ alignas(16) short Ks[64 * 128];   // [tok][d], swizzled
  __shared__ alignas(16) short Vt[128 * 64];   // [d][tok], swizzled
  __shared__ alignas(16) short Ps[4][16 * 64]; // per-wave P [qrow][tok], swizzled

  shortx8 qf[4];
  {
    long qrow = rowbase + q0 + w * 16 + l15;
    const unsigned short* qp = qkv + qrow * 6144 + qh * 128 + lg * 8;
#pragma unroll
    for (int dc = 0; dc < 4; ++dc) qf[dc] = *(const shortx8*)(qp + dc * 32);
  }

  floatx4 accO[8];
#pragma unroll
  for (int i = 0; i < 8; ++i) accO[i] = (floatx4)0.0f;
  float m_r[4], l_r[4];
#pragma unroll
  for (int r = 0; r < 4; ++r) { m_r[r] = -INFINITY; l_r[r] = 0.0f; }

  const int nt = qblk + 1;
  for (int t = 0; t < nt; ++t) {
    const int kt0 = t * 64;
    // ---- stage K [64][128]
#pragma unroll
    for (int i = 0; i < 4; ++i) {
      int ci = tid + 256 * i;
      int tok = ci >> 4, ch = ci & 15;
      uint4 v = *(const uint4*)(qkv + (rowbase + kt0 + tok) * 6144 + 4096 + kvh * 128 + ch * 8);
      int byte = (tok * 256 + ch * 16) ^ ((tok & 7) << 4);
      *(uint4*)((char*)Ks + byte) = v;
    }
    // ---- stage V transposed -> Vt[d][tok]
#pragma unroll
    for (int i = 0; i < 4; ++i) {
      int ci = tid + 256 * i;
      int tok = ci >> 4, ch = ci & 15;
      uint4 v = *(const uint4*)(qkv + (rowbase + kt0 + tok) * 6144 + 5120 + kvh * 128 + ch * 8);
      const unsigned short* e = (const unsigned short*)&v;
#pragma unroll
      for (int j = 0; j < 8; ++j) {
        int d = ch * 8 + j;
        int byte = (d * 128 + tok * 2) ^ (((d ^ (d >> 3)) & 7) << 4);
        *(short*)((char*)Vt + byte) = (short)e[j];
      }
    }
    __syncthreads();

    // ---- S = Q K^T
    floatx4 accS[4];
#pragma unroll
    for (int c = 0; c < 4; ++c) accS[c] = (floatx4)0.0f;
#pragma unroll
    for (int c = 0; c < 4; ++c) {
      int tok = c * 16 + l15;
      int rb = tok * 256, sw = (tok & 7) << 4;
#pragma unroll
      for (int dc = 0; dc < 4; ++dc) {
        shortx8 kf = *(const shortx8*)((char*)Ks + ((rb + dc * 64 + lg * 16) ^ sw));
        accS[c] = mfma16(qf[dc], kf, accS[c]);
      }
    }

    // ---- online softmax (rows live on 16-lane groups)
    float sv[4][4], rm[4];
    const int growb = q0 + w * 16 + lg * 4;
    const bool diag = (t == nt - 1);
#pragma unroll
    for (int r = 0; r < 4; ++r) rm[r] = -INFINITY;
#pragma unroll
    for (int c = 0; c < 4; ++c) {
      int gcol = kt0 + c * 16 + l15;
#pragma unroll
      for (int r = 0; r < 4; ++r) {
        float s = accS[c][r] * SCALE_QK;
        if (diag && gcol > growb + r) s = -1e30f;
        sv[c][r] = s;
        rm[r] = fmaxf(rm[r], s);
      }
    }
#pragma unroll
    for (int r = 0; r < 4; ++r) {
      rm[r] = fmaxf(rm[r], __shfl_xor(rm[r], 1));
      rm[r] = fmaxf(rm[r], __shfl_xor(rm[r], 2));
      rm[r] = fmaxf(rm[r], __shfl_xor(rm[r], 4));
      rm[r] = fmaxf(rm[r], __shfl_xor(rm[r], 8));
    }
    float alpha[4], rs[4], mn[4];
#pragma unroll
    for (int r = 0; r < 4; ++r) {
      mn[r] = fmaxf(m_r[r], rm[r]);
      alpha[r] = __expf(m_r[r] - mn[r]);
      rs[r] = 0.0f;
    }
    char* Pw = (char*)&Ps[w][0];
#pragma unroll
    for (int c = 0; c < 4; ++c) {
#pragma unroll
      for (int r = 0; r < 4; ++r) {
        float p = __expf(sv[c][r] - mn[r]);
        rs[r] += p;
        int row = lg * 4 + r, col = c * 16 + l15;
        int byte = (row * 128 + col * 2) ^ ((row & 7) << 4);
        *(short*)(Pw + byte) = (short)f2bf(p);
      }
    }
#pragma unroll
    for (int r = 0; r < 4; ++r) {
      rs[r] += __shfl_xor(rs[r], 1);
      rs[r] += __shfl_xor(rs[r], 2);
      rs[r] += __shfl_xor(rs[r], 4);
      rs[r] += __shfl_xor(rs[r], 8);
      l_r[r] = l_r[r] * alpha[r] + rs[r];
      m_r[r] = mn[r];
    }
#pragma unroll
    for (int db = 0; db < 8; ++db)
#pragma unroll
      for (int r = 0; r < 4; ++r) accO[db][r] *= alpha[r];

    // ---- O += P V
#pragma unroll
    for (int kc = 0; kc < 2; ++kc) {
      int pb = (l15 * 128 + kc * 64 + lg * 16) ^ ((l15 & 7) << 4);
      shortx8 pf = *(const shortx8*)(Pw + pb);
#pragma unroll
      for (int db = 0; db < 8; ++db) {
        int d = db * 16 + l15;
        int vb = (d * 128 + kc * 64 + lg * 16) ^ (((d ^ (d >> 3)) & 7) << 4);
        shortx8 vf = *(const shortx8*)((char*)Vt + vb);
        accO[db] = mfma16(pf, vf, accO[db]);
      }
    }
    __syncthreads();
  }

  // ---- epilogue: write O in place into q-region of qkv
  {
    long orow_base = rowbase + q0 + w * 16 + lg * 4;
#pragma unroll
    for (int r = 0; r < 4; ++r) {
      float inv_l = 1.0f / l_r[r];
      unsigned short* op = qkv + (orow_base + r) * 6144 + qh * 128 + l15;
#pragma unroll
      for (int db = 0; db < 8; ++db) op[db * 16] = f2bf(accO[db][r] * inv_l);
    }
  }
}

// ---------- launch ----------
extern "C" void kernel_launch(void* const* d_in, const int* in_sizes, int n_in,
                              void* d_out, int out_size, void* d_ws, size_t ws_size,
                              hipStream_t stream) {
  const float* x    = (const float*)d_in[0];
  const int*   posi = (const int*)d_in[1];
  const float* wqkv = (const float*)d_in[2];
  const float* wo   = (const float*)d_in[3];
  float* out = (float*)d_out;
  unsigned short* qkv = (unsigned short*)d_ws;   // [4096 tokens][6144] bf16 = 50.3 MB

  // qkv = x @ wqkv  (fp32->bf16 on the fly), M=4096 K=4096 N=6144
  gemm_kernel<0, 1><<<dim3(32, 48), 256, 0, stream>>>(
      (const void*)x, wqkv, (void*)qkv, 4096, 6144, 4096, 4096);
  // RoPE in place on q,k
  rope_kernel<<<dim3(4096), 256, 0, stream>>>(qkv, posi);
  // causal GQA attention; O overwrites q-region of qkv
  attn_kernel<<<dim3(32, 32, 2), 256, 0, stream>>>(qkv);
  // out = O @ wo ; A = qkv q-region (bf16, lda=6144), fp32 out
  gemm_kernel<1, 0><<<dim3(32, 32), 256, 0, stream>>>(
      (const void*)qkv, wo, (void*)out, 4096, 4096, 4096, 6144);
}

// Round 6
// 1295.772 us; speedup vs baseline: 1.3594x; 1.3594x over previous
//
#include <hip/hip_runtime.h>
#include <math.h>

// ---------- types / helpers ----------
typedef float  floatx4 __attribute__((ext_vector_type(4)));
typedef short  shortx8 __attribute__((ext_vector_type(8)));
typedef __bf16 bf16x8  __attribute__((ext_vector_type(8)));

static __device__ __forceinline__ floatx4 mfma16(shortx8 a, shortx8 b, floatx4 c) {
  return __builtin_amdgcn_mfma_f32_16x16x32_bf16(
      __builtin_bit_cast(bf16x8, a), __builtin_bit_cast(bf16x8, b), c, 0, 0, 0);
}
static __device__ __forceinline__ unsigned short f2bf(float f) {
  unsigned int u = __builtin_bit_cast(unsigned int, f);
  u += 0x7fffu + ((u >> 16) & 1u);           // RNE to bf16
  return (unsigned short)(u >> 16);
}
static __device__ __forceinline__ float bf2f(unsigned short h) {
  unsigned int u = ((unsigned int)h) << 16;
  return __builtin_bit_cast(float, u);
}
static __device__ __forceinline__ unsigned int packbf2(float lo, float hi) {
  return (unsigned int)f2bf(lo) | ((unsigned int)f2bf(hi) << 16);
}

#define GLOAD_LDS16(gp, lp) \
  __builtin_amdgcn_global_load_lds((const __attribute__((address_space(1))) void*)(gp), \
                                   (__attribute__((address_space(3))) void*)(lp), 16, 0, 0)

// ---------- fp32 -> bf16 elementwise convert (float4 / 8B-out per thread) ----------
__global__ __launch_bounds__(256) void conv_kernel(const float* __restrict__ in,
                                                   unsigned short* __restrict__ out, long n4) {
  long i = (long)blockIdx.x * 256 + threadIdx.x;
  if (i < n4) {
    float4 v = ((const float4*)in)[i];
    uint2 st;
    st.x = packbf2(v.x, v.y);
    st.y = packbf2(v.z, v.w);
    ((uint2*)out)[i] = st;
  }
}

// ---------- fp32 [R][C] -> bf16 [C][R] transpose-convert, 32x32 tiles via LDS ----------
__global__ __launch_bounds__(256) void tconv_kernel(const float* __restrict__ in,
                                                    unsigned short* __restrict__ out,
                                                    int R, int C) {
  __shared__ float t[32][33];
  const int r0 = blockIdx.x * 32, c0 = blockIdx.y * 32;
  const int tr = threadIdx.x >> 3, tq = threadIdx.x & 7;
  float4 v = *(const float4*)(in + (long)(r0 + tr) * C + c0 + tq * 4);
  t[tr][tq * 4 + 0] = v.x;
  t[tr][tq * 4 + 1] = v.y;
  t[tr][tq * 4 + 2] = v.z;
  t[tr][tq * 4 + 3] = v.w;
  __syncthreads();
  const int cl = tr, rq = tq;                 // write out[c0+cl][r0+rq*4 .. +3]
  uint2 st;
  st.x = packbf2(t[rq * 4 + 0][cl], t[rq * 4 + 1][cl]);
  st.y = packbf2(t[rq * 4 + 2][cl], t[rq * 4 + 3][cl]);
  *(uint2*)(out + (long)(c0 + cl) * R + r0 + rq * 4) = st;
}

// ---------- fast GEMM: C[M,Nn] = A[M,K] * BT[Nn,K]^T ; both operands bf16 row-major ----------
// 128x128 tile, BK=32, 4 waves (2x2). global_load_lds width-16 staging (m97 structure).
// k-chunk XOR swizzle (kc = j ^ ((row>>1)&3)) applied on the GLOBAL source so LDS stays
// linear for the DMA; ds_read_b128 fragment reads land on distinct bank-quads
// ({0,4,1,5,2,6,3,7} per 8-lane group) -> conflict-free.
template<int C_BF16>
__global__ __launch_bounds__(256) void gemm_tt(const unsigned short* __restrict__ A,
                                               const unsigned short* __restrict__ BT,
                                               void* __restrict__ Cp,
                                               int Nn, int K, int lda) {
  __shared__ alignas(16) short As[128 * 32];
  __shared__ alignas(16) short Bs[128 * 32];
  const int tid = threadIdx.x;
  const int lane = tid & 63, w = tid >> 6;
  const int l15 = lane & 15, lg = lane >> 4;
  const int wr = w >> 1, wc = w & 1;
  const int klg = lg ^ ((l15 >> 1) & 3);      // swizzled k-chunk for fragment reads
  const long m0 = (long)blockIdx.x * 128;
  const long n0 = (long)blockIdx.y * 128;

  floatx4 acc[4][4];
#pragma unroll
  for (int m = 0; m < 4; ++m)
#pragma unroll
    for (int n = 0; n < 4; ++n) acc[m][n] = (floatx4)0.0f;

  for (int k0 = 0; k0 < K; k0 += 32) {
#pragma unroll
    for (int i = 0; i < 2; ++i) {
      int c = i * 256 + tid;                  // 512 chunks of 16B per tile
      int row = c >> 2, j = c & 3;
      int kc = j ^ ((row >> 1) & 3);          // inverse swizzle on global source
      const unsigned short* ga = A + (m0 + row) * (long)lda + k0 + kc * 8;
      GLOAD_LDS16(ga, (char*)As + i * 4096 + w * 1024);
      const unsigned short* gb = BT + (n0 + row) * (long)K + k0 + kc * 8;
      GLOAD_LDS16(gb, (char*)Bs + i * 4096 + w * 1024);
    }
    __syncthreads();

    shortx8 afr[4], bfr[4];
#pragma unroll
    for (int m = 0; m < 4; ++m)
      afr[m] = *(const shortx8*)((char*)As + (wr * 64 + m * 16 + l15) * 64 + klg * 16);
#pragma unroll
    for (int n = 0; n < 4; ++n)
      bfr[n] = *(const shortx8*)((char*)Bs + (wc * 64 + n * 16 + l15) * 64 + klg * 16);
#pragma unroll
    for (int m = 0; m < 4; ++m)
#pragma unroll
      for (int n = 0; n < 4; ++n)
        acc[m][n] = mfma16(afr[m], bfr[n], acc[m][n]);
    __syncthreads();
  }

#pragma unroll
  for (int m = 0; m < 4; ++m)
#pragma unroll
    for (int n = 0; n < 4; ++n)
#pragma unroll
      for (int r = 0; r < 4; ++r) {
        long row = m0 + wr * 64 + m * 16 + lg * 4 + r;
        long col = n0 + wc * 64 + n * 16 + l15;
        float val = acc[m][n][r];
        if constexpr (C_BF16) ((unsigned short*)Cp)[row * Nn + col] = f2bf(val);
        else                  ((float*)Cp)[row * Nn + col] = val;
      }
}

// ---------- fallback GEMM (round-2 verified path; used only if ws too small) ----------
template<int A_BF16, int C_BF16>
__global__ __launch_bounds__(256) void gemm_fb(const void* __restrict__ Ap,
                                               const float* __restrict__ Bp,
                                               void* __restrict__ Cp,
                                               int M, int Nn, int K, int lda) {
  __shared__ alignas(16) short As[128 * 40];
  __shared__ alignas(16) short Bs[128 * 40];
  const int tid = threadIdx.x;
  const int lane = tid & 63, w = tid >> 6;
  const int l15 = lane & 15, lg = lane >> 4;
  const int wr = w >> 1, wc = w & 1;
  const long m0 = (long)blockIdx.x * 128;
  const long n0 = (long)blockIdx.y * 128;

  floatx4 acc[4][4];
#pragma unroll
  for (int m = 0; m < 4; ++m)
#pragma unroll
    for (int n = 0; n < 4; ++n) acc[m][n] = (floatx4)0.0f;

  for (int k0 = 0; k0 < K; k0 += 32) {
    if constexpr (A_BF16) {
      const unsigned short* A = (const unsigned short*)Ap;
#pragma unroll
      for (int i = 0; i < 2; ++i) {
        int qi = tid + 256 * i;
        int row = qi >> 2, ch = qi & 3;
        uint4 v = *(const uint4*)(A + (m0 + row) * (long)lda + k0 + ch * 8);
        *(uint4*)((char*)As + row * 80 + ch * 16) = v;
      }
    } else {
      const float* A = (const float*)Ap;
#pragma unroll
      for (int i = 0; i < 4; ++i) {
        int qi = tid + 256 * i;
        int row = qi >> 3, q = qi & 7;
        float4 v = *(const float4*)(A + (m0 + row) * (long)lda + k0 + q * 4);
        uint2 st;
        st.x = packbf2(v.x, v.y);
        st.y = packbf2(v.z, v.w);
        *(uint2*)((char*)As + row * 80 + q * 8) = st;
      }
    }
#pragma unroll
    for (int i = 0; i < 2; ++i) {
      int qi = tid + 256 * i;
      int kp = qi >> 5, q = qi & 31;
      const float* B0 = Bp + (long)(k0 + 2 * kp) * Nn + n0 + q * 4;
      float4 a = *(const float4*)B0;
      float4 b = *(const float4*)(B0 + Nn);
      const float* af_ = (const float*)&a;
      const float* bf_ = (const float*)&b;
#pragma unroll
      for (int j = 0; j < 4; ++j) {
        int col = q * 4 + j;
        *(unsigned int*)((char*)Bs + col * 80 + kp * 4) = packbf2(af_[j], bf_[j]);
      }
    }
    __syncthreads();

    shortx8 afr[4], bfr[4];
#pragma unroll
    for (int m = 0; m < 4; ++m)
      afr[m] = *(const shortx8*)((char*)As + (wr * 64 + m * 16 + l15) * 80 + lg * 16);
#pragma unroll
    for (int n = 0; n < 4; ++n)
      bfr[n] = *(const shortx8*)((char*)Bs + (wc * 64 + n * 16 + l15) * 80 + lg * 16);
#pragma unroll
    for (int m = 0; m < 4; ++m)
#pragma unroll
      for (int n = 0; n < 4; ++n)
        acc[m][n] = mfma16(afr[m], bfr[n], acc[m][n]);
    __syncthreads();
  }

#pragma unroll
  for (int m = 0; m < 4; ++m)
#pragma unroll
    for (int n = 0; n < 4; ++n)
#pragma unroll
      for (int r = 0; r < 4; ++r) {
        long row = m0 + wr * 64 + m * 16 + lg * 4 + r;
        long col = n0 + wc * 64 + n * 16 + l15;
        float val = acc[m][n][r];
        if constexpr (C_BF16) ((unsigned short*)Cp)[row * Nn + col] = f2bf(val);
        else                  ((float*)Cp)[row * Nn + col] = val;
      }
}

// ---------- RoPE (llama3 scaling), in-place on q (cols 0..4095) and k (4096..5119) ----------
__global__ __launch_bounds__(256) void rope_kernel(unsigned short* __restrict__ qkv,
                                                   const int* __restrict__ pos) {
  const int token = blockIdx.x;
  const int tid = threadIdx.x;
  __shared__ float cs[64], sn[64];
  if (tid < 64) {
    float d = (float)tid;
    float inv = powf(500000.0f, -d * (1.0f / 64.0f));
    float wl = 6.283185307179586f / inv;
    float scaled;
    if (wl > 8192.0f) scaled = inv * 0.125f;
    else if (wl < 2048.0f) scaled = inv;
    else {
      float smooth = (8192.0f / wl - 1.0f) * (1.0f / 3.0f);
      scaled = (1.0f - smooth) * inv * 0.125f + smooth * inv;
    }
    float ang = (float)pos[token] * scaled;
    cs[tid] = cosf(ang);
    sn[tid] = sinf(ang);
  }
  __syncthreads();
  const long base = (long)token * 6144;
#pragma unroll
  for (int it = 0; it < 10; ++it) {
    int p = tid + 256 * it;
    int h = p >> 6, d = p & 63;
    long i0 = base + h * 128 + d;
    float a = bf2f(qkv[i0]);
    float b = bf2f(qkv[i0 + 64]);
    float c = cs[d], s = sn[d];
    qkv[i0]      = f2bf(a * c - b * s);
    qkv[i0 + 64] = f2bf(b * c + a * s);
  }
}

// ---------- causal GQA flash attention (unchanged from round 2) ----------
#define SCALE_QK 0.08838834764831845f
__global__ __launch_bounds__(256) void attn_kernel(unsigned short* __restrict__ qkv) {
  const int tid = threadIdx.x;
  const int w = tid >> 6, lane = tid & 63;
  const int l15 = lane & 15, lg = lane >> 4;
  const int qblk = blockIdx.x, qh = blockIdx.y, b = blockIdx.z;
  const int kvh = qh >> 2;
  const int q0 = qblk * 64;
  const long rowbase = (long)b * 2048;

  __shared__ alignas(16) short Ks[64 * 128];
  __shared__ alignas(16) short Vt[128 * 64];
  __shared__ alignas(16) short Ps[4][16 * 64];

  shortx8 qf[4];
  {
    long qrow = rowbase + q0 + w * 16 + l15;
    const unsigned short* qp = qkv + qrow * 6144 + qh * 128 + lg * 8;
#pragma unroll
    for (int dc = 0; dc < 4; ++dc) qf[dc] = *(const shortx8*)(qp + dc * 32);
  }

  floatx4 accO[8];
#pragma unroll
  for (int i = 0; i < 8; ++i) accO[i] = (floatx4)0.0f;
  float m_r[4], l_r[4];
#pragma unroll
  for (int r = 0; r < 4; ++r) { m_r[r] = -INFINITY; l_r[r] = 0.0f; }

  const int nt = qblk + 1;
  for (int t = 0; t < nt; ++t) {
    const int kt0 = t * 64;
#pragma unroll
    for (int i = 0; i < 4; ++i) {
      int ci = tid + 256 * i;
      int tok = ci >> 4, ch = ci & 15;
      uint4 v = *(const uint4*)(qkv + (rowbase + kt0 + tok) * 6144 + 4096 + kvh * 128 + ch * 8);
      int byte = (tok * 256 + ch * 16) ^ ((tok & 7) << 4);
      *(uint4*)((char*)Ks + byte) = v;
    }
#pragma unroll
    for (int i = 0; i < 4; ++i) {
      int ci = tid + 256 * i;
      int tok = ci >> 4, ch = ci & 15;
      uint4 v = *(const uint4*)(qkv + (rowbase + kt0 + tok) * 6144 + 5120 + kvh * 128 + ch * 8);
      const unsigned short* e = (const unsigned short*)&v;
#pragma unroll
      for (int j = 0; j < 8; ++j) {
        int d = ch * 8 + j;
        int byte = (d * 128 + tok * 2) ^ (((d ^ (d >> 3)) & 7) << 4);
        *(short*)((char*)Vt + byte) = (short)e[j];
      }
    }
    __syncthreads();

    floatx4 accS[4];
#pragma unroll
    for (int c = 0; c < 4; ++c) accS[c] = (floatx4)0.0f;
#pragma unroll
    for (int c = 0; c < 4; ++c) {
      int tok = c * 16 + l15;
      int rb = tok * 256, sw = (tok & 7) << 4;
#pragma unroll
      for (int dc = 0; dc < 4; ++dc) {
        shortx8 kf = *(const shortx8*)((char*)Ks + ((rb + dc * 64 + lg * 16) ^ sw));
        accS[c] = mfma16(qf[dc], kf, accS[c]);
      }
    }

    float sv[4][4], rm[4];
    const int growb = q0 + w * 16 + lg * 4;
    const bool diag = (t == nt - 1);
#pragma unroll
    for (int r = 0; r < 4; ++r) rm[r] = -INFINITY;
#pragma unroll
    for (int c = 0; c < 4; ++c) {
      int gcol = kt0 + c * 16 + l15;
#pragma unroll
      for (int r = 0; r < 4; ++r) {
        float s = accS[c][r] * SCALE_QK;
        if (diag && gcol > growb + r) s = -1e30f;
        sv[c][r] = s;
        rm[r] = fmaxf(rm[r], s);
      }
    }
#pragma unroll
    for (int r = 0; r < 4; ++r) {
      rm[r] = fmaxf(rm[r], __shfl_xor(rm[r], 1));
      rm[r] = fmaxf(rm[r], __shfl_xor(rm[r], 2));
      rm[r] = fmaxf(rm[r], __shfl_xor(rm[r], 4));
      rm[r] = fmaxf(rm[r], __shfl_xor(rm[r], 8));
    }
    float alpha[4], rs[4], mn[4];
#pragma unroll
    for (int r = 0; r < 4; ++r) {
      mn[r] = fmaxf(m_r[r], rm[r]);
      alpha[r] = __expf(m_r[r] - mn[r]);
      rs[r] = 0.0f;
    }
    char* Pw = (char*)&Ps[w][0];
#pragma unroll
    for (int c = 0; c < 4; ++c) {
#pragma unroll
      for (int r = 0; r < 4; ++r) {
        float p = __expf(sv[c][r] - mn[r]);
        rs[r] += p;
        int row = lg * 4 + r, col = c * 16 + l15;
        int byte = (row * 128 + col * 2) ^ ((row & 7) << 4);
        *(short*)(Pw + byte) = (short)f2bf(p);
      }
    }
#pragma unroll
    for (int r = 0; r < 4; ++r) {
      rs[r] += __shfl_xor(rs[r], 1);
      rs[r] += __shfl_xor(rs[r], 2);
      rs[r] += __shfl_xor(rs[r], 4);
      rs[r] += __shfl_xor(rs[r], 8);
      l_r[r] = l_r[r] * alpha[r] + rs[r];
      m_r[r] = mn[r];
    }
#pragma unroll
    for (int db = 0; db < 8; ++db)
#pragma unroll
      for (int r = 0; r < 4; ++r) accO[db][r] *= alpha[r];

#pragma unroll
    for (int kc = 0; kc < 2; ++kc) {
      int pb = (l15 * 128 + kc * 64 + lg * 16) ^ ((l15 & 7) << 4);
      shortx8 pf = *(const shortx8*)(Pw + pb);
#pragma unroll
      for (int db = 0; db < 8; ++db) {
        int d = db * 16 + l15;
        int vb = (d * 128 + kc * 64 + lg * 16) ^ (((d ^ (d >> 3)) & 7) << 4);
        shortx8 vf = *(const shortx8*)((char*)Vt + vb);
        accO[db] = mfma16(pf, vf, accO[db]);
      }
    }
    __syncthreads();
  }

  {
    long orow_base = rowbase + q0 + w * 16 + lg * 4;
#pragma unroll
    for (int r = 0; r < 4; ++r) {
      float inv_l = 1.0f / l_r[r];
      unsigned short* op = qkv + (orow_base + r) * 6144 + qh * 128 + l15;
#pragma unroll
      for (int db = 0; db < 8; ++db) op[db * 16] = f2bf(accO[db][r] * inv_l);
    }
  }
}

// ---------- launch ----------
extern "C" void kernel_launch(void* const* d_in, const int* in_sizes, int n_in,
                              void* d_out, int out_size, void* d_ws, size_t ws_size,
                              hipStream_t stream) {
  const float* x    = (const float*)d_in[0];
  const int*   posi = (const int*)d_in[1];
  const float* wqkv = (const float*)d_in[2];
  const float* wo   = (const float*)d_in[3];
  float* out = (float*)d_out;
  unsigned short* qkv = (unsigned short*)d_ws;        // [4096][6144] bf16 = 50.3 MB

  const size_t off_wqT = 50331648;                    // wqkvT bf16 [6144][4096]
  const size_t off_xb  = off_wqT + 50331648;          // x bf16 [4096][4096]
  const size_t need    = off_xb + 33554432;           // 134,217,728 B

  if (ws_size >= need) {
    unsigned short* wqT = (unsigned short*)((char*)d_ws + off_wqT);
    unsigned short* xb  = (unsigned short*)((char*)d_ws + off_xb);
    unsigned short* woT = xb;                         // reuse x region after gemm1

    conv_kernel<<<dim3(16384), 256, 0, stream>>>(x, xb, 4194304);
    tconv_kernel<<<dim3(128, 192), 256, 0, stream>>>(wqkv, wqT, 4096, 6144);
    gemm_tt<1><<<dim3(32, 48), 256, 0, stream>>>(xb, wqT, (void*)qkv, 6144, 4096, 4096);
    rope_kernel<<<dim3(4096), 256, 0, stream>>>(qkv, posi);
    tconv_kernel<<<dim3(128, 128), 256, 0, stream>>>(wo, woT, 4096, 4096);
    attn_kernel<<<dim3(32, 32, 2), 256, 0, stream>>>(qkv);
    gemm_tt<0><<<dim3(32, 32), 256, 0, stream>>>(qkv, woT, (void*)out, 4096, 4096, 6144);
  } else {
    // fallback: round-2 verified path (ws only needs qkv)
    gemm_fb<0, 1><<<dim3(32, 48), 256, 0, stream>>>(
        (const void*)x, wqkv, (void*)qkv, 4096, 6144, 4096, 4096);
    rope_kernel<<<dim3(4096), 256, 0, stream>>>(qkv, posi);
    attn_kernel<<<dim3(32, 32, 2), 256, 0, stream>>>(qkv);
    gemm_fb<1, 0><<<dim3(32, 32), 256, 0, stream>>>(
        (const void*)qkv, wo, (void*)out, 4096, 4096, 4096, 6144);
  }
}

// Round 8
// 1176.971 us; speedup vs baseline: 1.4966x; 1.1009x over previous
//
#include <hip/hip_runtime.h>
#include <math.h>

// ---------- types / helpers ----------
typedef float  floatx4 __attribute__((ext_vector_type(4)));
typedef short  shortx8 __attribute__((ext_vector_type(8)));
typedef __bf16 bf16x8  __attribute__((ext_vector_type(8)));

static __device__ __forceinline__ floatx4 mfma16(shortx8 a, shortx8 b, floatx4 c) {
  return __builtin_amdgcn_mfma_f32_16x16x32_bf16(
      __builtin_bit_cast(bf16x8, a), __builtin_bit_cast(bf16x8, b), c, 0, 0, 0);
}
static __device__ __forceinline__ unsigned short f2bf(float f) {
  unsigned int u = __builtin_bit_cast(unsigned int, f);
  u += 0x7fffu + ((u >> 16) & 1u);           // RNE to bf16
  return (unsigned short)(u >> 16);
}
static __device__ __forceinline__ float bf2f(unsigned short h) {
  unsigned int u = ((unsigned int)h) << 16;
  return __builtin_bit_cast(float, u);
}
static __device__ __forceinline__ unsigned int packbf2(float lo, float hi) {
  return (unsigned int)f2bf(lo) | ((unsigned int)f2bf(hi) << 16);
}

#define GLOAD_LDS16(gp, lp) \
  __builtin_amdgcn_global_load_lds((const __attribute__((address_space(1))) void*)(gp), \
                                   (__attribute__((address_space(3))) void*)(lp), 16, 0, 0)

// ---------- fp32 -> bf16 elementwise convert ----------
__global__ __launch_bounds__(256) void conv_kernel(const float* __restrict__ in,
                                                   unsigned short* __restrict__ out, long n4) {
  long i = (long)blockIdx.x * 256 + threadIdx.x;
  if (i < n4) {
    float4 v = ((const float4*)in)[i];
    uint2 st;
    st.x = packbf2(v.x, v.y);
    st.y = packbf2(v.z, v.w);
    ((uint2*)out)[i] = st;
  }
}

// ---------- fp32 [R][C] -> bf16 [C][R] transpose-convert ----------
__global__ __launch_bounds__(256) void tconv_kernel(const float* __restrict__ in,
                                                    unsigned short* __restrict__ out,
                                                    int R, int C) {
  __shared__ float t[32][33];
  const int r0 = blockIdx.x * 32, c0 = blockIdx.y * 32;
  const int tr = threadIdx.x >> 3, tq = threadIdx.x & 7;
  float4 v = *(const float4*)(in + (long)(r0 + tr) * C + c0 + tq * 4);
  t[tr][tq * 4 + 0] = v.x;
  t[tr][tq * 4 + 1] = v.y;
  t[tr][tq * 4 + 2] = v.z;
  t[tr][tq * 4 + 3] = v.w;
  __syncthreads();
  const int cl = tr, rq = tq;
  uint2 st;
  st.x = packbf2(t[rq * 4 + 0][cl], t[rq * 4 + 1][cl]);
  st.y = packbf2(t[rq * 4 + 2][cl], t[rq * 4 + 3][cl]);
  *(uint2*)(out + (long)(c0 + cl) * R + r0 + rq * 4) = st;
}

// ---------- fast GEMM (verified R6): C = A * BT^T, bf16, global_load_lds staging ----------
template<int C_BF16>
__global__ __launch_bounds__(256) void gemm_tt(const unsigned short* __restrict__ A,
                                               const unsigned short* __restrict__ BT,
                                               void* __restrict__ Cp,
                                               int Nn, int K, int lda) {
  __shared__ alignas(16) short As[128 * 32];
  __shared__ alignas(16) short Bs[128 * 32];
  const int tid = threadIdx.x;
  const int lane = tid & 63, w = tid >> 6;
  const int l15 = lane & 15, lg = lane >> 4;
  const int wr = w >> 1, wc = w & 1;
  const int klg = lg ^ ((l15 >> 1) & 3);
  const long m0 = (long)blockIdx.x * 128;
  const long n0 = (long)blockIdx.y * 128;

  floatx4 acc[4][4];
#pragma unroll
  for (int m = 0; m < 4; ++m)
#pragma unroll
    for (int n = 0; n < 4; ++n) acc[m][n] = (floatx4)0.0f;

  for (int k0 = 0; k0 < K; k0 += 32) {
#pragma unroll
    for (int i = 0; i < 2; ++i) {
      int c = i * 256 + tid;
      int row = c >> 2, j = c & 3;
      int kc = j ^ ((row >> 1) & 3);
      const unsigned short* ga = A + (m0 + row) * (long)lda + k0 + kc * 8;
      GLOAD_LDS16(ga, (char*)As + i * 4096 + w * 1024);
      const unsigned short* gb = BT + (n0 + row) * (long)K + k0 + kc * 8;
      GLOAD_LDS16(gb, (char*)Bs + i * 4096 + w * 1024);
    }
    __syncthreads();

    shortx8 afr[4], bfr[4];
#pragma unroll
    for (int m = 0; m < 4; ++m)
      afr[m] = *(const shortx8*)((char*)As + (wr * 64 + m * 16 + l15) * 64 + klg * 16);
#pragma unroll
    for (int n = 0; n < 4; ++n)
      bfr[n] = *(const shortx8*)((char*)Bs + (wc * 64 + n * 16 + l15) * 64 + klg * 16);
#pragma unroll
    for (int m = 0; m < 4; ++m)
#pragma unroll
      for (int n = 0; n < 4; ++n)
        acc[m][n] = mfma16(afr[m], bfr[n], acc[m][n]);
    __syncthreads();
  }

#pragma unroll
  for (int m = 0; m < 4; ++m)
#pragma unroll
    for (int n = 0; n < 4; ++n)
#pragma unroll
      for (int r = 0; r < 4; ++r) {
        long row = m0 + wr * 64 + m * 16 + lg * 4 + r;
        long col = n0 + wc * 64 + n * 16 + l15;
        float val = acc[m][n][r];
        if constexpr (C_BF16) ((unsigned short*)Cp)[row * Nn + col] = f2bf(val);
        else                  ((float*)Cp)[row * Nn + col] = val;
      }
}

// ---------- fallback GEMM (R2-verified; used only if ws too small) ----------
template<int A_BF16, int C_BF16>
__global__ __launch_bounds__(256) void gemm_fb(const void* __restrict__ Ap,
                                               const float* __restrict__ Bp,
                                               void* __restrict__ Cp,
                                               int M, int Nn, int K, int lda) {
  __shared__ alignas(16) short As[128 * 40];
  __shared__ alignas(16) short Bs[128 * 40];
  const int tid = threadIdx.x;
  const int lane = tid & 63, w = tid >> 6;
  const int l15 = lane & 15, lg = lane >> 4;
  const int wr = w >> 1, wc = w & 1;
  const long m0 = (long)blockIdx.x * 128;
  const long n0 = (long)blockIdx.y * 128;

  floatx4 acc[4][4];
#pragma unroll
  for (int m = 0; m < 4; ++m)
#pragma unroll
    for (int n = 0; n < 4; ++n) acc[m][n] = (floatx4)0.0f;

  for (int k0 = 0; k0 < K; k0 += 32) {
    if constexpr (A_BF16) {
      const unsigned short* A = (const unsigned short*)Ap;
#pragma unroll
      for (int i = 0; i < 2; ++i) {
        int qi = tid + 256 * i;
        int row = qi >> 2, ch = qi & 3;
        uint4 v = *(const uint4*)(A + (m0 + row) * (long)lda + k0 + ch * 8);
        *(uint4*)((char*)As + row * 80 + ch * 16) = v;
      }
    } else {
      const float* A = (const float*)Ap;
#pragma unroll
      for (int i = 0; i < 4; ++i) {
        int qi = tid + 256 * i;
        int row = qi >> 3, q = qi & 7;
        float4 v = *(const float4*)(A + (m0 + row) * (long)lda + k0 + q * 4);
        uint2 st;
        st.x = packbf2(v.x, v.y);
        st.y = packbf2(v.z, v.w);
        *(uint2*)((char*)As + row * 80 + q * 8) = st;
      }
    }
#pragma unroll
    for (int i = 0; i < 2; ++i) {
      int qi = tid + 256 * i;
      int kp = qi >> 5, q = qi & 31;
      const float* B0 = Bp + (long)(k0 + 2 * kp) * Nn + n0 + q * 4;
      float4 a = *(const float4*)B0;
      float4 b = *(const float4*)(B0 + Nn);
      const float* af_ = (const float*)&a;
      const float* bf_ = (const float*)&b;
#pragma unroll
      for (int j = 0; j < 4; ++j) {
        int col = q * 4 + j;
        *(unsigned int*)((char*)Bs + col * 80 + kp * 4) = packbf2(af_[j], bf_[j]);
      }
    }
    __syncthreads();

    shortx8 afr[4], bfr[4];
#pragma unroll
    for (int m = 0; m < 4; ++m)
      afr[m] = *(const shortx8*)((char*)As + (wr * 64 + m * 16 + l15) * 80 + lg * 16);
#pragma unroll
    for (int n = 0; n < 4; ++n)
      bfr[n] = *(const shortx8*)((char*)Bs + (wc * 64 + n * 16 + l15) * 80 + lg * 16);
#pragma unroll
    for (int m = 0; m < 4; ++m)
#pragma unroll
      for (int n = 0; n < 4; ++n)
        acc[m][n] = mfma16(afr[m], bfr[n], acc[m][n]);
    __syncthreads();
  }

#pragma unroll
  for (int m = 0; m < 4; ++m)
#pragma unroll
    for (int n = 0; n < 4; ++n)
#pragma unroll
      for (int r = 0; r < 4; ++r) {
        long row = m0 + wr * 64 + m * 16 + lg * 4 + r;
        long col = n0 + wc * 64 + n * 16 + l15;
        float val = acc[m][n][r];
        if constexpr (C_BF16) ((unsigned short*)Cp)[row * Nn + col] = f2bf(val);
        else                  ((float*)Cp)[row * Nn + col] = val;
      }
}

// ---------- RoPE (llama3 scaling), in-place ----------
__global__ __launch_bounds__(256) void rope_kernel(unsigned short* __restrict__ qkv,
                                                   const int* __restrict__ pos) {
  const int token = blockIdx.x;
  const int tid = threadIdx.x;
  __shared__ float cs[64], sn[64];
  if (tid < 64) {
    float d = (float)tid;
    float inv = powf(500000.0f, -d * (1.0f / 64.0f));
    float wl = 6.283185307179586f / inv;
    float scaled;
    if (wl > 8192.0f) scaled = inv * 0.125f;
    else if (wl < 2048.0f) scaled = inv;
    else {
      float smooth = (8192.0f / wl - 1.0f) * (1.0f / 3.0f);
      scaled = (1.0f - smooth) * inv * 0.125f + smooth * inv;
    }
    float ang = (float)pos[token] * scaled;
    cs[tid] = cosf(ang);
    sn[tid] = sinf(ang);
  }
  __syncthreads();
  const long base = (long)token * 6144;
#pragma unroll
  for (int it = 0; it < 10; ++it) {
    int p = tid + 256 * it;
    int h = p >> 6, d = p & 63;
    long i0 = base + h * 128 + d;
    float a = bf2f(qkv[i0]);
    float b = bf2f(qkv[i0 + 64]);
    float c = cs[d], s = sn[d];
    qkv[i0]      = f2bf(a * c - b * s);
    qkv[i0 + 64] = f2bf(b * c + a * s);
  }
}

// ---------- causal GQA flash attention, GQA-grouped blocks ----------
// Block = (strip x, kvh, b), 4 waves. Wave w = q-head kvh*4+w, owns 32 q-rows
// (strip s covers rows [s*32, s*32+32)). K/V staged ONCE per GQA group (4x reuse).
// Strip remap s = 63-x: heavy strips dispatch first (LPT-ish tail).
#define SCALE_QK 0.08838834764831845f
__global__ __launch_bounds__(256) void attn_kernel(unsigned short* __restrict__ qkv) {
  const int tid = threadIdx.x;
  const int w = tid >> 6, lane = tid & 63;
  const int l15 = lane & 15, lg = lane >> 4;
  const int s = 63 - blockIdx.x;               // strip (32 q-rows), heavy-first
  const int kvh = blockIdx.y, b = blockIdx.z;
  const int h = kvh * 4 + w;                   // this wave's q-head
  const int q0 = s * 32;
  const long rowbase = (long)b * 2048;

  __shared__ alignas(16) short Ks[64 * 128];   // [tok][d], swizzled (16KB)
  __shared__ alignas(16) short Vt[128 * 64];   // [d][tok], swizzled (16KB)
  __shared__ alignas(16) short Ps[4][32 * 64]; // per-wave P [qrow][tok], swizzled (16KB)

  // Q fragments: 2 m-tiles x 4 k-chunks (read BEFORE any O write to q-region)
  shortx8 qf[2][4];
#pragma unroll
  for (int m = 0; m < 2; ++m) {
    long qrow = rowbase + q0 + m * 16 + l15;
    const unsigned short* qp = qkv + qrow * 6144 + h * 128 + lg * 8;
#pragma unroll
    for (int dc = 0; dc < 4; ++dc) qf[m][dc] = *(const shortx8*)(qp + dc * 32);
  }

  floatx4 accO[2][8];
#pragma unroll
  for (int m = 0; m < 2; ++m)
#pragma unroll
    for (int i = 0; i < 8; ++i) accO[m][i] = (floatx4)0.0f;
  float m_r[2][4], l_r[2][4];
#pragma unroll
  for (int m = 0; m < 2; ++m)
#pragma unroll
    for (int r = 0; r < 4; ++r) { m_r[m][r] = -INFINITY; l_r[m][r] = 0.0f; }

  const int nt = (s >> 1) + 1;                 // KV tiles of 64 toks
  char* Pw = (char*)&Ps[w][0];

  for (int t = 0; t < nt; ++t) {
    const int kt0 = t * 64;
    // ---- stage K [64][128] (shared by all 4 heads)
#pragma unroll
    for (int i = 0; i < 4; ++i) {
      int ci = tid + 256 * i;
      int tok = ci >> 4, ch = ci & 15;
      uint4 v = *(const uint4*)(qkv + (rowbase + kt0 + tok) * 6144 + 4096 + kvh * 128 + ch * 8);
      int byte = (tok * 256 + ch * 16) ^ ((tok & 7) << 4);
      *(uint4*)((char*)Ks + byte) = v;
    }
    // ---- stage V transposed -> Vt[d][tok], token-pairs packed as b32 writes
#pragma unroll
    for (int i = 0; i < 2; ++i) {
      int pu = tid + 256 * i;                  // 512 pair-units: 32 tok-pairs x 16 chunks
      int tp = pu >> 4, ch = pu & 15;
      const unsigned short* vrow = qkv + (rowbase + kt0 + 2 * tp) * 6144 + 5120 + kvh * 128 + ch * 8;
      uint4 a = *(const uint4*)(vrow);
      uint4 c2 = *(const uint4*)(vrow + 6144);
      const unsigned short* ea = (const unsigned short*)&a;
      const unsigned short* eb = (const unsigned short*)&c2;
#pragma unroll
      for (int j = 0; j < 8; ++j) {
        int d = ch * 8 + j;
        int byte = (d * 128 + tp * 4) ^ (((d ^ (d >> 3)) & 7) << 4);
        *(unsigned int*)((char*)Vt + byte) = (unsigned int)ea[j] | ((unsigned int)eb[j] << 16);
      }
    }
    __syncthreads();

    const bool diag = (t == nt - 1);
#pragma unroll
    for (int m = 0; m < 2; ++m) {
      // ---- S = Q K^T (16 rows x 64 toks)
      floatx4 accS[4];
#pragma unroll
      for (int c = 0; c < 4; ++c) accS[c] = (floatx4)0.0f;
#pragma unroll
      for (int c = 0; c < 4; ++c) {
        int tok = c * 16 + l15;
        int rb = tok * 256, sw = (tok & 7) << 4;
#pragma unroll
        for (int dc = 0; dc < 4; ++dc) {
          shortx8 kf = *(const shortx8*)((char*)Ks + ((rb + dc * 64 + lg * 16) ^ sw));
          accS[c] = mfma16(qf[m][dc], kf, accS[c]);
        }
      }

      // ---- online softmax
      float sv[4][4], rm[4];
      const int growb = q0 + m * 16 + lg * 4;
#pragma unroll
      for (int r = 0; r < 4; ++r) rm[r] = -INFINITY;
#pragma unroll
      for (int c = 0; c < 4; ++c) {
        int gcol = kt0 + c * 16 + l15;
#pragma unroll
        for (int r = 0; r < 4; ++r) {
          float sc = accS[c][r] * SCALE_QK;
          if (diag && gcol > growb + r) sc = -1e30f;
          sv[c][r] = sc;
          rm[r] = fmaxf(rm[r], sc);
        }
      }
#pragma unroll
      for (int r = 0; r < 4; ++r) {
        rm[r] = fmaxf(rm[r], __shfl_xor(rm[r], 1));
        rm[r] = fmaxf(rm[r], __shfl_xor(rm[r], 2));
        rm[r] = fmaxf(rm[r], __shfl_xor(rm[r], 4));
        rm[r] = fmaxf(rm[r], __shfl_xor(rm[r], 8));
      }
      float alpha[4], rs[4], mn[4];
#pragma unroll
      for (int r = 0; r < 4; ++r) {
        mn[r] = fmaxf(m_r[m][r], rm[r]);
        alpha[r] = __expf(m_r[m][r] - mn[r]);
        rs[r] = 0.0f;
      }
#pragma unroll
      for (int c = 0; c < 4; ++c) {
#pragma unroll
        for (int r = 0; r < 4; ++r) {
          float p = __expf(sv[c][r] - mn[r]);
          rs[r] += p;
          int row = m * 16 + lg * 4 + r, col = c * 16 + l15;
          int byte = (row * 128 + col * 2) ^ ((row & 7) << 4);
          *(short*)(Pw + byte) = (short)f2bf(p);
        }
      }
#pragma unroll
      for (int r = 0; r < 4; ++r) {
        rs[r] += __shfl_xor(rs[r], 1);
        rs[r] += __shfl_xor(rs[r], 2);
        rs[r] += __shfl_xor(rs[r], 4);
        rs[r] += __shfl_xor(rs[r], 8);
        l_r[m][r] = l_r[m][r] * alpha[r] + rs[r];
        m_r[m][r] = mn[r];
      }
#pragma unroll
      for (int db = 0; db < 8; ++db)
#pragma unroll
        for (int r = 0; r < 4; ++r) accO[m][db][r] *= alpha[r];

      // ---- O += P V
#pragma unroll
      for (int kc = 0; kc < 2; ++kc) {
        int prow = m * 16 + l15;
        int pb = (prow * 128 + kc * 64 + lg * 16) ^ ((l15 & 7) << 4);
        shortx8 pf = *(const shortx8*)(Pw + pb);
#pragma unroll
        for (int db = 0; db < 8; ++db) {
          int d = db * 16 + l15;
          int vb = (d * 128 + kc * 64 + lg * 16) ^ (((d ^ (d >> 3)) & 7) << 4);
          shortx8 vf = *(const shortx8*)((char*)Vt + vb);
          accO[m][db] = mfma16(pf, vf, accO[m][db]);
        }
      }
    }
    __syncthreads();
  }

  // ---- epilogue: O in place into the q-region (this block is sole reader/writer)
#pragma unroll
  for (int m = 0; m < 2; ++m) {
    long orow_base = rowbase + q0 + m * 16 + lg * 4;
#pragma unroll
    for (int r = 0; r < 4; ++r) {
      float inv_l = 1.0f / l_r[m][r];
      unsigned short* op = qkv + (orow_base + r) * 6144 + h * 128 + l15;
#pragma unroll
      for (int db = 0; db < 8; ++db) op[db * 16] = f2bf(accO[m][db][r] * inv_l);
    }
  }
}

// ---------- launch ----------
extern "C" void kernel_launch(void* const* d_in, const int* in_sizes, int n_in,
                              void* d_out, int out_size, void* d_ws, size_t ws_size,
                              hipStream_t stream) {
  const float* x    = (const float*)d_in[0];
  const int*   posi = (const int*)d_in[1];
  const float* wqkv = (const float*)d_in[2];
  const float* wo   = (const float*)d_in[3];
  float* out = (float*)d_out;
  unsigned short* qkv = (unsigned short*)d_ws;        // [4096][6144] bf16 = 50.3 MB

  const size_t off_wqT = 50331648;                    // wqkvT bf16 [6144][4096]
  const size_t off_xb  = off_wqT + 50331648;          // x bf16 [4096][4096]
  const size_t need    = off_xb + 33554432;           // 134,217,728 B

  if (ws_size >= need) {
    unsigned short* wqT = (unsigned short*)((char*)d_ws + off_wqT);
    unsigned short* xb  = (unsigned short*)((char*)d_ws + off_xb);
    unsigned short* woT = xb;                         // reuse x region after gemm1

    conv_kernel<<<dim3(16384), 256, 0, stream>>>(x, xb, 4194304);
    tconv_kernel<<<dim3(128, 192), 256, 0, stream>>>(wqkv, wqT, 4096, 6144);
    gemm_tt<1><<<dim3(32, 48), 256, 0, stream>>>(xb, wqT, (void*)qkv, 6144, 4096, 4096);
    rope_kernel<<<dim3(4096), 256, 0, stream>>>(qkv, posi);
    tconv_kernel<<<dim3(128, 128), 256, 0, stream>>>(wo, woT, 4096, 4096);
    attn_kernel<<<dim3(64, 8, 2), 256, 0, stream>>>(qkv);
    gemm_tt<0><<<dim3(32, 32), 256, 0, stream>>>(qkv, woT, (void*)out, 4096, 4096, 6144);
  } else {
    // fallback: R2-verified path (ws only needs qkv)
    gemm_fb<0, 1><<<dim3(32, 48), 256, 0, stream>>>(
        (const void*)x, wqkv, (void*)qkv, 4096, 6144, 4096, 4096);
    rope_kernel<<<dim3(4096), 256, 0, stream>>>(qkv, posi);
    attn_kernel<<<dim3(64, 8, 2), 256, 0, stream>>>(qkv);
    gemm_fb<1, 0><<<dim3(32, 32), 256, 0, stream>>>(
        (const void*)qkv, wo, (void*)out, 4096, 4096, 4096, 6144);
  }
}